// Round 1
// baseline (630.262 us; speedup 1.0000x reference)
//
#include <hip/hip_runtime.h>
#include <cstdint>

#define NN 100000
#define NE 1600000
#define INDIM 165
#define HID 64

constexpr int SCAN_TPB = 256;
constexpr int SCAN_ITEMS = 8;
constexpr int SCAN_BLK = SCAN_TPB * SCAN_ITEMS; // 2048

// ---------------- CSR build ----------------

__global__ void k_deg(const int* __restrict__ dst, int* __restrict__ deg, int ne) {
    for (int e = blockIdx.x * blockDim.x + threadIdx.x; e < ne; e += gridDim.x * blockDim.x)
        atomicAdd(&deg[dst[e]], 1);
}

__global__ void k_scan1(const int* __restrict__ in, int* __restrict__ out,
                        int* __restrict__ bsum, int n) {
    __shared__ int wsum[SCAN_TPB / 64];
    const int tid = threadIdx.x;
    const int lane = tid & 63, wid = tid >> 6;
    const int base = blockIdx.x * SCAN_BLK + tid * SCAN_ITEMS;
    int v[SCAN_ITEMS];
    int tsum = 0;
#pragma unroll
    for (int i = 0; i < SCAN_ITEMS; ++i) {
        int idx = base + i;
        v[i] = (idx < n) ? in[idx] : 0;
        tsum += v[i];
    }
    // inclusive wave scan of tsum
    int x = tsum;
#pragma unroll
    for (int off = 1; off < 64; off <<= 1) {
        int y = __shfl_up(x, off, 64);
        if (lane >= off) x += y;
    }
    if (lane == 63) wsum[wid] = x;
    __syncthreads();
    int woff = 0;
#pragma unroll
    for (int w = 0; w < SCAN_TPB / 64; ++w)
        if (w < wid) woff += wsum[w];
    int run = woff + x - tsum; // exclusive prefix for this thread
#pragma unroll
    for (int i = 0; i < SCAN_ITEMS; ++i) {
        int idx = base + i;
        if (idx < n) out[idx] = run;
        run += v[i];
    }
    if (tid == SCAN_TPB - 1) bsum[blockIdx.x] = woff + x; // block total
}

__global__ void k_scan2(int* bsum, int nb) {
    const int lane = threadIdx.x; // blockDim = 64, nb <= 64
    int v = (lane < nb) ? bsum[lane] : 0;
    int x = v;
#pragma unroll
    for (int off = 1; off < 64; off <<= 1) {
        int y = __shfl_up(x, off, 64);
        if (lane >= off) x += y;
    }
    if (lane < nb) bsum[lane] = x - v; // exclusive
    if (lane == nb - 1) bsum[nb] = x;  // grand total
}

__global__ void k_scan3(int* __restrict__ out, const int* __restrict__ bsum, int n, int nb) {
    const int off = bsum[blockIdx.x];
#pragma unroll
    for (int i = 0; i < SCAN_ITEMS; ++i) {
        int id = blockIdx.x * SCAN_BLK + i * SCAN_TPB + threadIdx.x;
        if (id < n) out[id] += off;
    }
    if (blockIdx.x == 0 && threadIdx.x == 0) out[n] = bsum[nb];
}

__global__ void k_copy(const int* __restrict__ a, int* __restrict__ b, int n) {
    int i = blockIdx.x * blockDim.x + threadIdx.x;
    if (i < n) b[i] = a[i];
}

__global__ void k_fill(const int* __restrict__ src, const int* __restrict__ dst,
                       int* __restrict__ cursor, int* __restrict__ col, int ne) {
    for (int e = blockIdx.x * blockDim.x + threadIdx.x; e < ne; e += gridDim.x * blockDim.x) {
        int d = dst[e];
        int p = atomicAdd(&cursor[d], 1);
        col[p] = src[e];
    }
}

// ---------------- fused dual linear: Y = X@Wl, R = X@Wr ----------------
// 1 wave (64 threads) per 64 nodes. x-tile transposed into LDS with XOR
// swizzle (conflict-free writes AND reads, zero padding -> 16 KB LDS).
// W rows are wave-uniform -> scalar loads; 128 fp32 accumulators in VGPRs.

template <int K>
__global__ __launch_bounds__(64) void k_linear(const float* __restrict__ X,
                                               const float* __restrict__ Wl,
                                               const float* __restrict__ Wr,
                                               float* __restrict__ Y,
                                               float* __restrict__ R, int n) {
    __shared__ float xs[64 * 64];
    const int lane = threadIdx.x;
    const int nodeBase = blockIdx.x * 64;

    float accL[64], accR[64];
#pragma unroll
    for (int t = 0; t < 64; ++t) { accL[t] = 0.f; accR[t] = 0.f; }

    for (int c = 0; c < K; c += 64) {
        const int kw = (K - c < 64) ? (K - c) : 64;
        __syncthreads();
        if (lane < kw) {
#pragma unroll 4
            for (int nn = 0; nn < 64; ++nn) {
                int node = nodeBase + nn;
                if (node >= n) node = n - 1;
                xs[lane * 64 + (nn ^ lane)] = X[(size_t)node * K + c + lane];
            }
        }
        __syncthreads();
        for (int kk = 0; kk < kw; ++kk) {
            const float xv = xs[kk * 64 + (lane ^ kk)];
            const float* __restrict__ wl = Wl + (size_t)(c + kk) * HID;
            const float* __restrict__ wr = Wr + (size_t)(c + kk) * HID;
#pragma unroll
            for (int t = 0; t < 64; ++t) accL[t] = fmaf(xv, wl[t], accL[t]);
#pragma unroll
            for (int t = 0; t < 64; ++t) accR[t] = fmaf(xv, wr[t], accR[t]);
        }
    }

    // epilogue: transpose through LDS, coalesced stores
    __syncthreads();
#pragma unroll
    for (int t = 0; t < 64; ++t) xs[t * 64 + (lane ^ t)] = accL[t];
    __syncthreads();
    for (int r = 0; r < 64; ++r) {
        int node = nodeBase + r;
        if (node < n) Y[(size_t)node * HID + lane] = xs[lane * 64 + (r ^ lane)];
    }
    __syncthreads();
#pragma unroll
    for (int t = 0; t < 64; ++t) xs[t * 64 + (lane ^ t)] = accR[t];
    __syncthreads();
    for (int r = 0; r < 64; ++r) {
        int node = nodeBase + r;
        if (node < n) R[(size_t)node * HID + lane] = xs[lane * 64 + (r ^ lane)];
    }
}

// ---------------- aggregation (+ optional fused classifier) ----------------
// 1 wave per dst node, lane = feature dim. Coalesced 256B gathers of Y rows.

template <bool CLS>
__global__ __launch_bounds__(256) void k_agg(const float* __restrict__ Y,
                                             const float* __restrict__ Rm,
                                             const float* __restrict__ bias,
                                             const int* __restrict__ rowptr,
                                             const int* __restrict__ col,
                                             float* __restrict__ H,
                                             const float* __restrict__ Wc,
                                             const float* __restrict__ bc,
                                             float* __restrict__ out, int n) {
    const int lane = threadIdx.x & 63;
    const int node = blockIdx.x * 4 + (threadIdx.x >> 6);
    if (node >= n) return;
    const int s = rowptr[node], e = rowptr[node + 1];
    float a0 = 0.f, a1 = 0.f, a2 = 0.f, a3 = 0.f;
    int i = s;
    for (; i + 3 < e; i += 4) {
        int s0 = col[i], s1 = col[i + 1], s2 = col[i + 2], s3 = col[i + 3];
        a0 += Y[(size_t)s0 * HID + lane];
        a1 += Y[(size_t)s1 * HID + lane];
        a2 += Y[(size_t)s2 * HID + lane];
        a3 += Y[(size_t)s3 * HID + lane];
    }
    for (; i < e; ++i) a0 += Y[(size_t)col[i] * HID + lane];
    float acc = (a0 + a1) + (a2 + a3);
    const int deg = e - s;
    float h = acc / (float)(deg > 1 ? deg : 1) + bias[lane] + Rm[(size_t)node * HID + lane];
    h = fmaxf(h, 0.f);
    if (!CLS) {
        H[(size_t)node * HID + lane] = h;
    } else {
        float p0 = h * Wc[lane * 2 + 0];
        float p1 = h * Wc[lane * 2 + 1];
#pragma unroll
        for (int off = 32; off > 0; off >>= 1) {
            p0 += __shfl_xor(p0, off, 64);
            p1 += __shfl_xor(p1, off, 64);
        }
        if (lane == 0) {
            out[(size_t)node * 2 + 0] = p0 + bc[0];
            out[(size_t)node * 2 + 1] = p1 + bc[1];
        }
    }
}

// ---------------- launch ----------------

extern "C" void kernel_launch(void* const* d_in, const int* in_sizes, int n_in,
                              void* d_out, int out_size, void* d_ws, size_t ws_size,
                              hipStream_t stream) {
    const float* x   = (const float*)d_in[0];
    const int*   ei  = (const int*)d_in[1];
    const float* W1l = (const float*)d_in[2];
    const float* b1  = (const float*)d_in[3];
    const float* W1r = (const float*)d_in[4];
    const float* W2l = (const float*)d_in[5];
    const float* b2  = (const float*)d_in[6];
    const float* W2r = (const float*)d_in[7];
    const float* Wc  = (const float*)d_in[8];
    const float* bc  = (const float*)d_in[9];
    float* out = (float*)d_out;
    const int* src = ei;
    const int* dst = ei + NE;

    char* base = (char*)d_ws;
    size_t off = 0;
    auto alloc = [&](size_t bytes) {
        void* p = base + off;
        off = (off + bytes + 255) & ~(size_t)255;
        return p;
    };
    int*   deg    = (int*)alloc((size_t)NN * 4);
    int*   rowptr = (int*)alloc((size_t)(NN + 1) * 4);
    int*   cursor = (int*)alloc((size_t)NN * 4);
    int*   bsum   = (int*)alloc(256 * 4);
    int*   col    = (int*)alloc((size_t)NE * 4);
    float* Y      = (float*)alloc((size_t)NN * HID * 4);
    float* R      = (float*)alloc((size_t)NN * HID * 4);
    float* H1     = (float*)alloc((size_t)NN * HID * 4);

    const int nb = (NN + SCAN_BLK - 1) / SCAN_BLK; // 49

    hipMemsetAsync(deg, 0, (size_t)NN * 4, stream);
    k_deg<<<1024, 256, 0, stream>>>(dst, deg, NE);
    k_scan1<<<nb, SCAN_TPB, 0, stream>>>(deg, rowptr, bsum, NN);
    k_scan2<<<1, 64, 0, stream>>>(bsum, nb);
    k_scan3<<<nb, SCAN_TPB, 0, stream>>>(rowptr, bsum, NN, nb);
    k_copy<<<(NN + 255) / 256, 256, 0, stream>>>(rowptr, cursor, NN);
    k_fill<<<1024, 256, 0, stream>>>(src, dst, cursor, col, NE);

    k_linear<INDIM><<<(NN + 63) / 64, 64, 0, stream>>>(x, W1l, W1r, Y, R, NN);
    k_agg<false><<<(NN + 3) / 4, 256, 0, stream>>>(Y, R, b1, rowptr, col, H1,
                                                   nullptr, nullptr, nullptr, NN);
    k_linear<HID><<<(NN + 63) / 64, 64, 0, stream>>>(H1, W2l, W2r, Y, R, NN);
    k_agg<true><<<(NN + 3) / 4, 256, 0, stream>>>(Y, R, b2, rowptr, col, nullptr,
                                                  Wc, bc, out, NN);
}